// Round 4
// baseline (813.746 us; speedup 1.0000x reference)
//
#include <hip/hip_runtime.h>

// Workspace layout (~232 MiB):
//   [0, 256K)      a_scores  fp32 [2][32][1024]   (zeroed, atomic accum)
//   [256K, 512K)   softmax w fp32 [2][32][1024]
//   [512K, 640K)   acc       fp32 [2][32][512]    (zeroed; seqmean + vector)
//   [768K, 774K)   bias_cat  fp32 [1536]
//   [1M, 2.5M)     Wt bf16   [1536][512]  (Wt[w*512+n][k] = W_w[k][n])
//   [4M, 36M)      Xb2 bf16  [32768][512]  (seq2 converted)
//   [40M, 232M)    qkv bf16  [6][32768][512]  slots: q1,k1,v1,q2,k2,v2
// Xb1 (seq1 bf16) is written into d_in[1] (seq2 fp32, dead after Xb2 pass).
// GEMMs are LDS-free: fragments load straight global->VGPR (K-major layout
// makes each lane's 16B fragment contiguous); no __syncthreads in K-loop.

typedef __bf16 bf16x8_t __attribute__((ext_vector_type(8)));
typedef float f32x4_t __attribute__((ext_vector_type(4)));

__device__ __forceinline__ unsigned short f2bf(float f) {
    union { float f; unsigned int u; } c; c.f = f;
    unsigned int u = c.u;
    unsigned int r = (u + 0x7FFFu + ((u >> 16) & 1u)) >> 16;  // RNE
    return (unsigned short)r;
}
__device__ __forceinline__ float bf2f(unsigned short h) {
    union { unsigned int u; float f; } c; c.u = ((unsigned int)h) << 16;
    return c.f;
}
__device__ __forceinline__ float fast_tanh(float x) {
    float e = __expf(2.f * x);                       // inf for large x -> tanh=1
    return 1.f - 2.f * __builtin_amdgcn_rcpf(e + 1.f);
}

// ---------------- Kernel 0: seq fp32 -> bf16, fused seq-mean -------------
__global__ __launch_bounds__(256) void x2bf_kernel(
    const float* __restrict__ src, unsigned short* __restrict__ dst,
    float* __restrict__ accv)
{
    int chunk = blockIdx.x;   // 0..7 (128 rows each)
    int b = blockIdx.y;       // 0..31
    int tid = threadIdx.x, lane = tid & 63, wv = tid >> 6;
    __shared__ float red[4][512];
    float sum[8] = {};
    size_t base = ((size_t)b * 1024 + (size_t)chunk * 128) * 512;
    #pragma unroll 4
    for (int i = 0; i < 32; ++i) {
        int r = i * 4 + wv;
        size_t ro = base + (size_t)r * 512;
        float4 a = *reinterpret_cast<const float4*>(&src[ro + lane * 4]);
        float4 c = *reinterpret_cast<const float4*>(&src[ro + 256 + lane * 4]);
        ushort4 ha; ha.x = f2bf(a.x); ha.y = f2bf(a.y); ha.z = f2bf(a.z); ha.w = f2bf(a.w);
        ushort4 hc; hc.x = f2bf(c.x); hc.y = f2bf(c.y); hc.z = f2bf(c.z); hc.w = f2bf(c.w);
        *reinterpret_cast<ushort4*>(&dst[ro + lane * 4]) = ha;
        *reinterpret_cast<ushort4*>(&dst[ro + 256 + lane * 4]) = hc;
        sum[0] += a.x; sum[1] += a.y; sum[2] += a.z; sum[3] += a.w;
        sum[4] += c.x; sum[5] += c.y; sum[6] += c.z; sum[7] += c.w;
    }
    #pragma unroll
    for (int t = 0; t < 4; ++t) {
        red[wv][lane * 4 + t] = sum[t];
        red[wv][256 + lane * 4 + t] = sum[4 + t];
    }
    __syncthreads();
    #pragma unroll
    for (int j = 0; j < 2; ++j) {
        int col = tid + j * 256;
        float s = red[0][col] + red[1][col] + red[2][col] + red[3][col];
        atomicAdd(&accv[(size_t)b * 512 + col], s * (1.f / 1024.f));
    }
}

// ---------------- Kernel 1: W [k][n] fp32 -> Wt [n][k] bf16 --------------
__global__ __launch_bounds__(256) void wconv_kernel(
    const float* __restrict__ Wq, const float* __restrict__ Wk,
    const float* __restrict__ Wv, unsigned short* __restrict__ Wt)
{
    const float* W = (blockIdx.z == 0) ? Wq : (blockIdx.z == 1) ? Wk : Wv;
    unsigned short* o = Wt + (size_t)blockIdx.z * 512 * 512;
    __shared__ unsigned short t[64][65];
    int k0 = blockIdx.x * 64, n0 = blockIdx.y * 64;
    #pragma unroll
    for (int i = 0; i < 16; ++i) {
        int idx = i * 256 + threadIdx.x;
        int r = idx >> 6, c = idx & 63;
        t[r][c] = f2bf(W[(size_t)(k0 + r) * 512 + n0 + c]);
    }
    __syncthreads();
    #pragma unroll
    for (int i = 0; i < 16; ++i) {
        int idx = i * 256 + threadIdx.x;
        int r = idx >> 6, c = idx & 63;   // r = n, c = k
        o[(size_t)(n0 + r) * 512 + k0 + c] = t[c][r];
    }
}

__global__ __launch_bounds__(512) void biascat_kernel(
    const float* __restrict__ bq, const float* __restrict__ bk,
    const float* __restrict__ bv, float* __restrict__ bc)
{
    int n = threadIdx.x;
    bc[n] = bq[n]; bc[512 + n] = bk[n]; bc[1024 + n] = bv[n];
}

// ---------------- Kernel 2: QKV projection GEMM (LDS-free) ---------------
// 128x128 block = 2x2 waves of 64x64. Fragments direct global->VGPR.
__global__ __launch_bounds__(256, 2) void qkv_gemm(
    const unsigned short* __restrict__ Xb1, const unsigned short* __restrict__ Xb2,
    const unsigned short* __restrict__ Wt, const float* __restrict__ bias_cat,
    unsigned short* __restrict__ qkv)
{
    int mg = blockIdx.x * 128;          // 0..65535 global row
    int z = mg >> 15;                   // which sequence
    int mr = mg & 32767;                // row within sequence
    int nb = blockIdx.y * 128;          // 0..1535 column

    int tid = threadIdx.x;
    int lane = tid & 63, wv = tid >> 6;
    int wm = wv >> 1, wn = wv & 1;
    int q = lane >> 4, ln = lane & 15;

    const unsigned short* X = z ? Xb2 : Xb1;
    // per-lane fragment base pointers (16B contiguous per lane)
    const unsigned short* pA = X + (size_t)(mr + wm * 64 + ln) * 512 + q * 8;
    const unsigned short* pB = Wt + (size_t)(nb + wn * 64 + ln) * 512 + q * 8;

    f32x4_t acc[4][4] = {};
    bf16x8_t A0[4], B0[4], A1[4], B1[4];

    auto loadf = [&](bf16x8_t* A, bf16x8_t* B, int k0) {
        #pragma unroll
        for (int i = 0; i < 4; ++i)
            A[i] = *reinterpret_cast<const bf16x8_t*>(pA + (size_t)i * 16 * 512 + k0);
        #pragma unroll
        for (int j = 0; j < 4; ++j)
            B[j] = *reinterpret_cast<const bf16x8_t*>(pB + (size_t)j * 16 * 512 + k0);
    };
    auto domfma = [&](bf16x8_t* A, bf16x8_t* B) {
        #pragma unroll
        for (int i = 0; i < 4; ++i)
            #pragma unroll
            for (int j = 0; j < 4; ++j)
                acc[i][j] = __builtin_amdgcn_mfma_f32_16x16x32_bf16(
                    A[i], B[j], acc[i][j], 0, 0, 0);
    };

    loadf(A0, B0, 0);
    #pragma unroll
    for (int it = 0; it < 8; ++it) {
        loadf(A1, B1, it * 64 + 32);
        domfma(A0, B0);
        if (it < 7) loadf(A0, B0, it * 64 + 64);
        domfma(A1, B1);
    }

    #pragma unroll
    for (int j = 0; j < 4; ++j) {
        int n = nb + wn * 64 + j * 16 + ln;
        int w = n >> 9, col = n & 511;
        float bb = bias_cat[n];
        unsigned short* out = qkv + (size_t)(z * 3 + w) * 32768 * 512;
        #pragma unroll
        for (int i = 0; i < 4; ++i) {
            int mb = mr + wm * 64 + i * 16 + q * 4;
            #pragma unroll
            for (int r = 0; r < 4; ++r)
                out[(size_t)(mb + r) * 512 + col] =
                    f2bf(fmaxf(acc[i][j][r] + bb, 0.f));
        }
    }
}

// ---------------- Kernel 3: score GEMM + tanh + row-sum (LDS-free) -------
// a[z][s] += sum_t tanh( K_self[s,:] . Q_other[t,:] )
__global__ __launch_bounds__(256, 2) void score_kernel(
    const unsigned short* __restrict__ qkv, float* __restrict__ a_out)
{
    int st = blockIdx.x;          // 0..15  (64-row s tile)
    int tg = blockIdx.y;          // 0..3   (256-col t group; wave takes 64)
    int z = blockIdx.z;           // 0..63
    int which = z >> 5, b = z & 31;
    const unsigned short* Am =
        qkv + ((size_t)(which ? 4 : 1) * 32768 + (size_t)b * 1024) * 512;
    const unsigned short* Bm =
        qkv + ((size_t)(which ? 0 : 3) * 32768 + (size_t)b * 1024) * 512;

    int tid = threadIdx.x;
    int lane = tid & 63, wv = tid >> 6;
    int q = lane >> 4, ln = lane & 15;
    int s0 = st * 64;
    int t0 = tg * 256 + wv * 64;

    const unsigned short* pA = Am + (size_t)(s0 + ln) * 512 + q * 8;
    const unsigned short* pB = Bm + (size_t)(t0 + ln) * 512 + q * 8;

    f32x4_t acc[4][4] = {};
    bf16x8_t A0[4], B0[4], A1[4], B1[4];

    auto loadf = [&](bf16x8_t* A, bf16x8_t* B, int k0) {
        #pragma unroll
        for (int i = 0; i < 4; ++i)
            A[i] = *reinterpret_cast<const bf16x8_t*>(pA + (size_t)i * 16 * 512 + k0);
        #pragma unroll
        for (int j = 0; j < 4; ++j)
            B[j] = *reinterpret_cast<const bf16x8_t*>(pB + (size_t)j * 16 * 512 + k0);
    };
    auto domfma = [&](bf16x8_t* A, bf16x8_t* B) {
        #pragma unroll
        for (int i = 0; i < 4; ++i)
            #pragma unroll
            for (int j = 0; j < 4; ++j)
                acc[i][j] = __builtin_amdgcn_mfma_f32_16x16x32_bf16(
                    A[i], B[j], acc[i][j], 0, 0, 0);
    };

    loadf(A0, B0, 0);
    #pragma unroll
    for (int it = 0; it < 8; ++it) {
        loadf(A1, B1, it * 64 + 32);
        domfma(A0, B0);
        if (it < 7) loadf(A0, B0, it * 64 + 64);
        domfma(A1, B1);
    }

    // acc[i][j][r]: row s = s0 + i*16 + q*4 + r, col t = t0 + j*16 + ln
    #pragma unroll
    for (int i = 0; i < 4; ++i) {
        #pragma unroll
        for (int r = 0; r < 4; ++r) {
            float s = 0.f;
            #pragma unroll
            for (int j = 0; j < 4; ++j) s += fast_tanh(acc[i][j][r]);
            #pragma unroll
            for (int off = 1; off <= 8; off <<= 1) s += __shfl_xor(s, off, 64);
            if (ln == 0)
                atomicAdd(&a_out[(size_t)z * 1024 + s0 + i * 16 + q * 4 + r], s);
        }
    }
}

// ---------------- Kernel 4: masked softmax over S=1024 -------------------
__global__ __launch_bounds__(256) void softmax_kernel(
    const float* __restrict__ a_in, const int* __restrict__ mask1,
    const int* __restrict__ mask2, float* __restrict__ w_out)
{
    int z = blockIdx.x, which = z >> 5, b = z & 31;
    const int* mask = (which ? mask2 : mask1) + (size_t)b * 1024;
    const float* a = a_in + (size_t)z * 1024;
    float* w = w_out + (size_t)z * 1024;
    int tid = threadIdx.x, lane = tid & 63, wv = tid >> 6;

    float vals[4];
    #pragma unroll
    for (int j = 0; j < 4; ++j) {
        int s = tid + j * 256;
        vals[j] = mask[s] ? -__builtin_inff() : a[s];
    }
    float m = fmaxf(fmaxf(vals[0], vals[1]), fmaxf(vals[2], vals[3]));
    #pragma unroll
    for (int off = 32; off; off >>= 1) m = fmaxf(m, __shfl_xor(m, off, 64));
    __shared__ float redm[4], redsum[4];
    if (lane == 0) redm[wv] = m;
    __syncthreads();
    m = fmaxf(fmaxf(redm[0], redm[1]), fmaxf(redm[2], redm[3]));

    float e[4], sum = 0.f;
    #pragma unroll
    for (int j = 0; j < 4; ++j) { e[j] = __expf(vals[j] - m); sum += e[j]; }
    #pragma unroll
    for (int off = 32; off; off >>= 1) sum += __shfl_xor(sum, off, 64);
    if (lane == 0) redsum[wv] = sum;
    __syncthreads();
    sum = redsum[0] + redsum[1] + redsum[2] + redsum[3];
    float inv = 1.f / sum;
    #pragma unroll
    for (int j = 0; j < 4; ++j) w[tid + j * 256] = e[j] * inv;
}

// --------- Kernel 5: acc[z][d] += sum_s w[s]*v[s,d] ----------------------
__global__ __launch_bounds__(512) void wsum_kernel(
    const unsigned short* __restrict__ qkv, const float* __restrict__ w_in,
    float* __restrict__ acc)
{
    int chunk = blockIdx.x;           // 0..7, 128 rows each
    int z = blockIdx.y, which = z >> 5, b = z & 31;
    const unsigned short* V =
        qkv + ((size_t)(which ? 5 : 2) * 32768 + (size_t)b * 1024) * 512;
    const float* w = w_in + (size_t)z * 1024;
    int d = threadIdx.x;
    float a = 0.f;
    int s0 = chunk * 128;
    for (int s = s0; s < s0 + 128; ++s)
        a += w[s] * bf2f(V[(size_t)s * 512 + d]);
    atomicAdd(&acc[(size_t)z * 512 + d], a);
}

// ---------------- Kernel 6: LayerNorm over D=512 -------------------------
__global__ __launch_bounds__(512) void ln_kernel(
    const float* __restrict__ acc, const float* __restrict__ gamma,
    const float* __restrict__ beta, float* __restrict__ out)
{
    int z = blockIdx.x, d = threadIdx.x;
    int lane = d & 63, wv = d >> 6;
    float x = acc[(size_t)z * 512 + d];
    float s = x;
    #pragma unroll
    for (int off = 32; off; off >>= 1) s += __shfl_xor(s, off, 64);
    __shared__ float red[8], red2[8];
    if (lane == 0) red[wv] = s;
    __syncthreads();
    float mu = 0.f;
    #pragma unroll
    for (int i = 0; i < 8; ++i) mu += red[i];
    mu *= (1.f / 512.f);
    float c = x - mu;
    float s2 = c * c;
    #pragma unroll
    for (int off = 32; off; off >>= 1) s2 += __shfl_xor(s2, off, 64);
    if (lane == 0) red2[wv] = s2;
    __syncthreads();
    float var = 0.f;
    #pragma unroll
    for (int i = 0; i < 8; ++i) var += red2[i];
    var *= (1.f / 512.f);
    out[(size_t)z * 512 + d] = c * __frsqrt_rn(var + 1e-5f) * gamma[d] + beta[d];
}

extern "C" void kernel_launch(void* const* d_in, const int* in_sizes, int n_in,
                              void* d_out, int out_size, void* d_ws, size_t ws_size,
                              hipStream_t stream) {
    const float* seq1 = (const float*)d_in[0];
    const float* seq2 = (const float*)d_in[1];
    const int* mask1 = (const int*)d_in[2];
    const int* mask2 = (const int*)d_in[3];
    const float* Wq = (const float*)d_in[4];
    const float* bq = (const float*)d_in[5];
    const float* Wk = (const float*)d_in[6];
    const float* bk = (const float*)d_in[7];
    const float* Wv = (const float*)d_in[8];
    const float* bv = (const float*)d_in[9];
    const float* gamma = (const float*)d_in[10];
    const float* beta = (const float*)d_in[11];
    float* out = (float*)d_out;

    char* ws = (char*)d_ws;
    float* a_sc = (float*)(ws);                              // 256 KB
    float* wsm = (float*)(ws + (256u << 10));                // 256 KB
    float* accv = (float*)(ws + (512u << 10));               // 128 KB
    float* bias_cat = (float*)(ws + (768u << 10));           // 6 KB
    unsigned short* Wt = (unsigned short*)(ws + (1u << 20)); // 1.5 MB
    unsigned short* Xb2 = (unsigned short*)(ws + (4ull << 20));   // 32 MB
    unsigned short* qkv = (unsigned short*)(ws + (40ull << 20));  // 192 MB
    unsigned short* Xb1 = (unsigned short*)d_in[1];  // reuse dead seq2 fp32 buf

    hipMemsetAsync(ws, 0, 640u << 10, stream);  // zero a_sc + wsm + accv

    wconv_kernel<<<dim3(8, 8, 3), 256, 0, stream>>>(Wq, Wk, Wv, Wt);
    biascat_kernel<<<1, 512, 0, stream>>>(bq, bk, bv, bias_cat);
    // seq2 first (reads d_in[1]); then seq1 overwrites d_in[1] with bf16 X1
    x2bf_kernel<<<dim3(8, 32), 256, 0, stream>>>(seq2, Xb2, accv + 32 * 512);
    x2bf_kernel<<<dim3(8, 32), 256, 0, stream>>>(seq1, Xb1, accv);
    qkv_gemm<<<dim3(512, 12), 256, 0, stream>>>(Xb1, Xb2, Wt, bias_cat, qkv);
    score_kernel<<<dim3(16, 4, 64), 256, 0, stream>>>(qkv, a_sc);
    softmax_kernel<<<64, 256, 0, stream>>>(a_sc, mask1, mask2, wsm);
    wsum_kernel<<<dim3(8, 64), 512, 0, stream>>>(qkv, wsm, accv);
    ln_kernel<<<64, 512, 0, stream>>>(accv, gamma, beta, out);
}

// Round 5
// 470.482 us; speedup vs baseline: 1.7296x; 1.7296x over previous
//
#include <hip/hip_runtime.h>

// Workspace layout (~232 MiB):
//   [0, 256K)      a_scores  fp32 [2][32][1024]   (zeroed, atomic accum)
//   [256K, 512K)   softmax w fp32 [2][32][1024]
//   [512K, 640K)   acc       fp32 [2][32][512]    (zeroed; seqmean + vector)
//   [768K, 774K)   bias_cat  fp32 [1536]
//   [1M, 2.5M)     Wt bf16   [1536][512]  (Wt[w*512+n][k] = W_w[k][n])
//   [4M, 36M)      Xb2 bf16  [32768][512]  (seq2 converted)
//   [40M, 232M)    qkv bf16  [6][32768][512]  slots: q1,k1,v1,q2,k2,v2
// Xb1 (seq1 bf16) is written into d_in[1] (seq2 fp32, dead after Xb2 pass).
// GEMM structure: m97 2-barrier, 128x128 tile, 4 waves 64x64, BK=32,
// both operands staged via global_load_lds width=16.

typedef __bf16 bf16x8_t __attribute__((ext_vector_type(8)));
typedef float f32x4_t __attribute__((ext_vector_type(4)));

__device__ __forceinline__ unsigned short f2bf(float f) {
    union { float f; unsigned int u; } c; c.f = f;
    unsigned int u = c.u;
    unsigned int r = (u + 0x7FFFu + ((u >> 16) & 1u)) >> 16;  // RNE
    return (unsigned short)r;
}
__device__ __forceinline__ float bf2f(unsigned short h) {
    union { unsigned int u; float f; } c; c.u = ((unsigned int)h) << 16;
    return c.f;
}
__device__ __forceinline__ void gl2lds16(const void* g, void* l) {
    __builtin_amdgcn_global_load_lds(
        (const __attribute__((address_space(1))) void*)g,
        (__attribute__((address_space(3))) void*)l, 16, 0, 0);
}
__device__ __forceinline__ float fast_tanh(float x) {
    float e = __expf(2.f * x);                       // inf for large x -> tanh=1
    return 1.f - 2.f * __builtin_amdgcn_rcpf(e + 1.f);
}

// ---------------- Kernel 0: seq fp32 -> bf16, fused seq-mean -------------
__global__ __launch_bounds__(256) void x2bf_kernel(
    const float* __restrict__ src, unsigned short* __restrict__ dst,
    float* __restrict__ accv)
{
    int chunk = blockIdx.x;   // 0..7 (128 rows each)
    int b = blockIdx.y;       // 0..31
    int tid = threadIdx.x, lane = tid & 63, wv = tid >> 6;
    __shared__ float red[4][512];
    float sum[8] = {};
    size_t base = ((size_t)b * 1024 + (size_t)chunk * 128) * 512;
    #pragma unroll 4
    for (int i = 0; i < 32; ++i) {
        int r = i * 4 + wv;
        size_t ro = base + (size_t)r * 512;
        float4 a = *reinterpret_cast<const float4*>(&src[ro + lane * 4]);
        float4 c = *reinterpret_cast<const float4*>(&src[ro + 256 + lane * 4]);
        ushort4 ha; ha.x = f2bf(a.x); ha.y = f2bf(a.y); ha.z = f2bf(a.z); ha.w = f2bf(a.w);
        ushort4 hc; hc.x = f2bf(c.x); hc.y = f2bf(c.y); hc.z = f2bf(c.z); hc.w = f2bf(c.w);
        *reinterpret_cast<ushort4*>(&dst[ro + lane * 4]) = ha;
        *reinterpret_cast<ushort4*>(&dst[ro + 256 + lane * 4]) = hc;
        sum[0] += a.x; sum[1] += a.y; sum[2] += a.z; sum[3] += a.w;
        sum[4] += c.x; sum[5] += c.y; sum[6] += c.z; sum[7] += c.w;
    }
    #pragma unroll
    for (int t = 0; t < 4; ++t) {
        red[wv][lane * 4 + t] = sum[t];
        red[wv][256 + lane * 4 + t] = sum[4 + t];
    }
    __syncthreads();
    #pragma unroll
    for (int j = 0; j < 2; ++j) {
        int col = tid + j * 256;
        float s = red[0][col] + red[1][col] + red[2][col] + red[3][col];
        atomicAdd(&accv[(size_t)b * 512 + col], s * (1.f / 1024.f));
    }
}

// ---------------- Kernel 1: W [k][n] fp32 -> Wt [n][k] bf16 --------------
__global__ __launch_bounds__(256) void wconv_kernel(
    const float* __restrict__ Wq, const float* __restrict__ Wk,
    const float* __restrict__ Wv, unsigned short* __restrict__ Wt)
{
    const float* W = (blockIdx.z == 0) ? Wq : (blockIdx.z == 1) ? Wk : Wv;
    unsigned short* o = Wt + (size_t)blockIdx.z * 512 * 512;
    __shared__ unsigned short t[64][65];
    int k0 = blockIdx.x * 64, n0 = blockIdx.y * 64;
    #pragma unroll
    for (int i = 0; i < 16; ++i) {
        int idx = i * 256 + threadIdx.x;
        int r = idx >> 6, c = idx & 63;
        t[r][c] = f2bf(W[(size_t)(k0 + r) * 512 + n0 + c]);
    }
    __syncthreads();
    #pragma unroll
    for (int i = 0; i < 16; ++i) {
        int idx = i * 256 + threadIdx.x;
        int r = idx >> 6, c = idx & 63;   // r = n, c = k
        o[(size_t)(n0 + r) * 512 + k0 + c] = t[c][r];
    }
}

__global__ __launch_bounds__(512) void biascat_kernel(
    const float* __restrict__ bq, const float* __restrict__ bk,
    const float* __restrict__ bv, float* __restrict__ bc)
{
    int n = threadIdx.x;
    bc[n] = bq[n]; bc[512 + n] = bk[n]; bc[1024 + n] = bv[n];
}

// ---------------- Kernel 2: QKV projection GEMM (m97 structure) ----------
// C = relu(X @ [Wq|Wk|Wv] + b) -> bf16 slots. 128x128 tile, 4 waves 64x64.
__global__ __launch_bounds__(256) void qkv_gemm(
    const unsigned short* __restrict__ Xb1, const unsigned short* __restrict__ Xb2,
    const unsigned short* __restrict__ Wt, const float* __restrict__ bias_cat,
    unsigned short* __restrict__ qkv)
{
    int nt = blockIdx.x;          // 0..11  (fastest: co-resident blocks share A)
    int mg = blockIdx.y;          // 0..511
    int z = mg >> 8;              // which sequence
    int m0 = (mg & 255) * 128;    // row within sequence
    int n0 = nt * 128;

    const unsigned short* X = z ? Xb2 : Xb1;

    __shared__ alignas(16) unsigned short As[128 * 32];
    __shared__ alignas(16) unsigned short Bs[128 * 32];

    int tid = threadIdx.x;
    int lane = tid & 63, wv = tid >> 6;
    int wm = wv >> 1, wn = wv & 1;
    int q = lane >> 4, ln = lane & 15;

    f32x4_t acc[4][4] = {};

    for (int k0 = 0; k0 < 512; k0 += 32) {
        #pragma unroll
        for (int j = 0; j < 2; ++j) {
            int cbase = j * 256 + wv * 64;
            int c = cbase + lane;
            int row = c >> 2, k8 = (c & 3) * 8;
            gl2lds16(&X[(size_t)(m0 + row) * 512 + k0 + k8], &As[cbase * 8]);
            gl2lds16(&Wt[(size_t)(n0 + row) * 512 + k0 + k8], &Bs[cbase * 8]);
        }
        __syncthreads();

        bf16x8_t af[4], bfr[4];
        #pragma unroll
        for (int i = 0; i < 4; ++i)
            af[i] = *reinterpret_cast<const bf16x8_t*>(
                &As[(wm * 64 + i * 16 + ln) * 32 + q * 8]);
        #pragma unroll
        for (int j = 0; j < 4; ++j)
            bfr[j] = *reinterpret_cast<const bf16x8_t*>(
                &Bs[(wn * 64 + j * 16 + ln) * 32 + q * 8]);
        #pragma unroll
        for (int i = 0; i < 4; ++i)
            #pragma unroll
            for (int j = 0; j < 4; ++j)
                acc[i][j] = __builtin_amdgcn_mfma_f32_16x16x32_bf16(
                    af[i], bfr[j], acc[i][j], 0, 0, 0);
        __syncthreads();
    }

    #pragma unroll
    for (int j = 0; j < 4; ++j) {
        int n = n0 + wn * 64 + j * 16 + ln;
        int w = n >> 9, col = n & 511;
        float bb = bias_cat[n];
        unsigned short* out = qkv + (size_t)(z * 3 + w) * 32768 * 512;
        #pragma unroll
        for (int i = 0; i < 4; ++i) {
            int mb = m0 + wm * 64 + i * 16 + q * 4;
            #pragma unroll
            for (int r = 0; r < 4; ++r)
                out[(size_t)(mb + r) * 512 + col] =
                    f2bf(fmaxf(acc[i][j][r] + bb, 0.f));
        }
    }
}

// ---------------- Kernel 3: score GEMM + tanh + row-sum (m97) ------------
// a[which][b][s] += sum_t tanh( A[s,:] . B[t,:] ),  A=k_self, B=q_other
__global__ __launch_bounds__(256) void score_kernel(
    const unsigned short* __restrict__ qkv, float* __restrict__ a_out)
{
    int tt = blockIdx.x, st = blockIdx.y, z = blockIdx.z;
    int which = z >> 5, b = z & 31;
    const unsigned short* Am =
        qkv + ((size_t)(which ? 4 : 1) * 32768 + (size_t)b * 1024) * 512;
    const unsigned short* Bm =
        qkv + ((size_t)(which ? 0 : 3) * 32768 + (size_t)b * 1024) * 512;

    __shared__ alignas(16) unsigned short As[128 * 32];
    __shared__ alignas(16) unsigned short Bs[128 * 32];

    int tid = threadIdx.x;
    int lane = tid & 63, wv = tid >> 6;
    int wm = wv >> 1, wn = wv & 1;
    int q = lane >> 4, ln = lane & 15;
    int s0 = st * 128, t0 = tt * 128;

    f32x4_t acc[4][4] = {};

    for (int k0 = 0; k0 < 512; k0 += 32) {
        #pragma unroll
        for (int j = 0; j < 2; ++j) {
            int cbase = j * 256 + wv * 64;
            int c = cbase + lane;
            int row = c >> 2, kk8 = (c & 3) * 8;
            gl2lds16(&Am[(size_t)(s0 + row) * 512 + k0 + kk8], &As[cbase * 8]);
            gl2lds16(&Bm[(size_t)(t0 + row) * 512 + k0 + kk8], &Bs[cbase * 8]);
        }
        __syncthreads();

        bf16x8_t af[4], bfr[4];
        #pragma unroll
        for (int i = 0; i < 4; ++i)
            af[i] = *reinterpret_cast<const bf16x8_t*>(
                &As[(wm * 64 + i * 16 + ln) * 32 + q * 8]);
        #pragma unroll
        for (int j = 0; j < 4; ++j)
            bfr[j] = *reinterpret_cast<const bf16x8_t*>(
                &Bs[(wn * 64 + j * 16 + ln) * 32 + q * 8]);
        #pragma unroll
        for (int i = 0; i < 4; ++i)
            #pragma unroll
            for (int j = 0; j < 4; ++j)
                acc[i][j] = __builtin_amdgcn_mfma_f32_16x16x32_bf16(
                    af[i], bfr[j], acc[i][j], 0, 0, 0);
        __syncthreads();
    }

    #pragma unroll
    for (int i = 0; i < 4; ++i) {
        #pragma unroll
        for (int r = 0; r < 4; ++r) {
            float s = 0.f;
            #pragma unroll
            for (int j = 0; j < 4; ++j) s += fast_tanh(acc[i][j][r]);
            #pragma unroll
            for (int off = 1; off <= 8; off <<= 1) s += __shfl_xor(s, off, 64);
            if (ln == 0)
                atomicAdd(&a_out[(size_t)z * 1024 + s0 + wm * 64 + i * 16 + q * 4 + r], s);
        }
    }
}

// ---------------- Kernel 4: masked softmax over S=1024 -------------------
__global__ __launch_bounds__(256) void softmax_kernel(
    const float* __restrict__ a_in, const int* __restrict__ mask1,
    const int* __restrict__ mask2, float* __restrict__ w_out)
{
    int z = blockIdx.x, which = z >> 5, b = z & 31;
    const int* mask = (which ? mask2 : mask1) + (size_t)b * 1024;
    const float* a = a_in + (size_t)z * 1024;
    float* w = w_out + (size_t)z * 1024;
    int tid = threadIdx.x, lane = tid & 63, wv = tid >> 6;

    float vals[4];
    #pragma unroll
    for (int j = 0; j < 4; ++j) {
        int s = tid + j * 256;
        vals[j] = mask[s] ? -__builtin_inff() : a[s];
    }
    float m = fmaxf(fmaxf(vals[0], vals[1]), fmaxf(vals[2], vals[3]));
    #pragma unroll
    for (int off = 32; off; off >>= 1) m = fmaxf(m, __shfl_xor(m, off, 64));
    __shared__ float redm[4], redsum[4];
    if (lane == 0) redm[wv] = m;
    __syncthreads();
    m = fmaxf(fmaxf(redm[0], redm[1]), fmaxf(redm[2], redm[3]));

    float e[4], sum = 0.f;
    #pragma unroll
    for (int j = 0; j < 4; ++j) { e[j] = __expf(vals[j] - m); sum += e[j]; }
    #pragma unroll
    for (int off = 32; off; off >>= 1) sum += __shfl_xor(sum, off, 64);
    if (lane == 0) redsum[wv] = sum;
    __syncthreads();
    sum = redsum[0] + redsum[1] + redsum[2] + redsum[3];
    float inv = 1.f / sum;
    #pragma unroll
    for (int j = 0; j < 4; ++j) w[tid + j * 256] = e[j] * inv;
}

// --------- Kernel 5: acc[z][d] += sum_s w[s]*v[s,d] ----------------------
__global__ __launch_bounds__(512) void wsum_kernel(
    const unsigned short* __restrict__ qkv, const float* __restrict__ w_in,
    float* __restrict__ acc)
{
    int chunk = blockIdx.x;           // 0..7, 128 rows each
    int z = blockIdx.y, which = z >> 5, b = z & 31;
    const unsigned short* V =
        qkv + ((size_t)(which ? 5 : 2) * 32768 + (size_t)b * 1024) * 512;
    const float* w = w_in + (size_t)z * 1024;
    int d = threadIdx.x;
    float a = 0.f;
    int s0 = chunk * 128;
    for (int s = s0; s < s0 + 128; ++s)
        a += w[s] * bf2f(V[(size_t)s * 512 + d]);
    atomicAdd(&acc[(size_t)z * 512 + d], a);
}

// ---------------- Kernel 6: LayerNorm over D=512 -------------------------
__global__ __launch_bounds__(512) void ln_kernel(
    const float* __restrict__ acc, const float* __restrict__ gamma,
    const float* __restrict__ beta, float* __restrict__ out)
{
    int z = blockIdx.x, d = threadIdx.x;
    int lane = d & 63, wv = d >> 6;
    float x = acc[(size_t)z * 512 + d];
    float s = x;
    #pragma unroll
    for (int off = 32; off; off >>= 1) s += __shfl_xor(s, off, 64);
    __shared__ float red[8], red2[8];
    if (lane == 0) red[wv] = s;
    __syncthreads();
    float mu = 0.f;
    #pragma unroll
    for (int i = 0; i < 8; ++i) mu += red[i];
    mu *= (1.f / 512.f);
    float c = x - mu;
    float s2 = c * c;
    #pragma unroll
    for (int off = 32; off; off >>= 1) s2 += __shfl_xor(s2, off, 64);
    if (lane == 0) red2[wv] = s2;
    __syncthreads();
    float var = 0.f;
    #pragma unroll
    for (int i = 0; i < 8; ++i) var += red2[i];
    var *= (1.f / 512.f);
    out[(size_t)z * 512 + d] = c * __frsqrt_rn(var + 1e-5f) * gamma[d] + beta[d];
}

extern "C" void kernel_launch(void* const* d_in, const int* in_sizes, int n_in,
                              void* d_out, int out_size, void* d_ws, size_t ws_size,
                              hipStream_t stream) {
    const float* seq1 = (const float*)d_in[0];
    const float* seq2 = (const float*)d_in[1];
    const int* mask1 = (const int*)d_in[2];
    const int* mask2 = (const int*)d_in[3];
    const float* Wq = (const float*)d_in[4];
    const float* bq = (const float*)d_in[5];
    const float* Wk = (const float*)d_in[6];
    const float* bk = (const float*)d_in[7];
    const float* Wv = (const float*)d_in[8];
    const float* bv = (const float*)d_in[9];
    const float* gamma = (const float*)d_in[10];
    const float* beta = (const float*)d_in[11];
    float* out = (float*)d_out;

    char* ws = (char*)d_ws;
    float* a_sc = (float*)(ws);                              // 256 KB
    float* wsm = (float*)(ws + (256u << 10));                // 256 KB
    float* accv = (float*)(ws + (512u << 10));               // 128 KB
    float* bias_cat = (float*)(ws + (768u << 10));           // 6 KB
    unsigned short* Wt = (unsigned short*)(ws + (1u << 20)); // 1.5 MB
    unsigned short* Xb2 = (unsigned short*)(ws + (4ull << 20));   // 32 MB
    unsigned short* qkv = (unsigned short*)(ws + (40ull << 20));  // 192 MB
    unsigned short* Xb1 = (unsigned short*)d_in[1];  // reuse dead seq2 fp32 buf

    hipMemsetAsync(ws, 0, 640u << 10, stream);  // zero a_sc + wsm + accv

    wconv_kernel<<<dim3(8, 8, 3), 256, 0, stream>>>(Wq, Wk, Wv, Wt);
    biascat_kernel<<<1, 512, 0, stream>>>(bq, bk, bv, bias_cat);
    // seq2 first (reads d_in[1]); then seq1 overwrites d_in[1] with bf16 X1
    x2bf_kernel<<<dim3(8, 32), 256, 0, stream>>>(seq2, Xb2, accv + 32 * 512);
    x2bf_kernel<<<dim3(8, 32), 256, 0, stream>>>(seq1, Xb1, accv);
    qkv_gemm<<<dim3(12, 512), 256, 0, stream>>>(Xb1, Xb2, Wt, bias_cat, qkv);
    score_kernel<<<dim3(8, 8, 64), 256, 0, stream>>>(qkv, a_sc);
    softmax_kernel<<<64, 256, 0, stream>>>(a_sc, mask1, mask2, wsm);
    wsum_kernel<<<dim3(8, 64), 512, 0, stream>>>(qkv, wsm, accv);
    ln_kernel<<<64, 512, 0, stream>>>(accv, gamma, beta, out);
}

// Round 6
// 469.470 us; speedup vs baseline: 1.7333x; 1.0022x over previous
//
#include <hip/hip_runtime.h>

// Workspace layout (~232 MiB):
//   [0, 256K)      a_scores  fp32 [2][32][1024]   (zeroed, atomic accum)
//   [256K, 512K)   softmax w fp32 [2][32][1024]
//   [512K, 640K)   acc       fp32 [2][32][512]    (zeroed; seqmean + vector)
//   [768K, 774K)   bias_cat  fp32 [1536]
//   [1M, 2.5M)     Wt bf16   [1536][512]  (Wt[w*512+n][k] = W_w[k][n])
//   [4M, 36M)      Xb2 bf16  [32768][512]  (seq2 converted)
//   [40M, 232M)    qkv bf16  [6][32768][512]  slots: q1,k1,v1,q2,k2,v2
// Xb1 (seq1 bf16) is written into d_in[1] (seq2 fp32, dead after Xb2 pass).
// GEMM structure: m97 2-barrier, 128x128 tile, 4 waves 64x64, BK=32,
// both operands staged via global_load_lds width=16.
// qkv epilogue: LDS-staged, coalesced 16B row stores (avoids 2B scatter RMW).

typedef __bf16 bf16x8_t __attribute__((ext_vector_type(8)));
typedef float f32x4_t __attribute__((ext_vector_type(4)));

__device__ __forceinline__ unsigned short f2bf(float f) {
    union { float f; unsigned int u; } c; c.f = f;
    unsigned int u = c.u;
    unsigned int r = (u + 0x7FFFu + ((u >> 16) & 1u)) >> 16;  // RNE
    return (unsigned short)r;
}
__device__ __forceinline__ float bf2f(unsigned short h) {
    union { unsigned int u; float f; } c; c.u = ((unsigned int)h) << 16;
    return c.f;
}
__device__ __forceinline__ void gl2lds16(const void* g, void* l) {
    __builtin_amdgcn_global_load_lds(
        (const __attribute__((address_space(1))) void*)g,
        (__attribute__((address_space(3))) void*)l, 16, 0, 0);
}
__device__ __forceinline__ float fast_tanh(float x) {
    float e = __expf(2.f * x);                       // inf for large x -> tanh=1
    return 1.f - 2.f * __builtin_amdgcn_rcpf(e + 1.f);
}

// ---------------- Kernel 0: seq fp32 -> bf16, fused seq-mean -------------
__global__ __launch_bounds__(256) void x2bf_kernel(
    const float* __restrict__ src, unsigned short* __restrict__ dst,
    float* __restrict__ accv)
{
    int chunk = blockIdx.x;   // 0..7 (128 rows each)
    int b = blockIdx.y;       // 0..31
    int tid = threadIdx.x, lane = tid & 63, wv = tid >> 6;
    __shared__ float red[4][512];
    float sum[8] = {};
    size_t base = ((size_t)b * 1024 + (size_t)chunk * 128) * 512;
    #pragma unroll 4
    for (int i = 0; i < 32; ++i) {
        int r = i * 4 + wv;
        size_t ro = base + (size_t)r * 512;
        float4 a = *reinterpret_cast<const float4*>(&src[ro + lane * 4]);
        float4 c = *reinterpret_cast<const float4*>(&src[ro + 256 + lane * 4]);
        ushort4 ha; ha.x = f2bf(a.x); ha.y = f2bf(a.y); ha.z = f2bf(a.z); ha.w = f2bf(a.w);
        ushort4 hc; hc.x = f2bf(c.x); hc.y = f2bf(c.y); hc.z = f2bf(c.z); hc.w = f2bf(c.w);
        *reinterpret_cast<ushort4*>(&dst[ro + lane * 4]) = ha;
        *reinterpret_cast<ushort4*>(&dst[ro + 256 + lane * 4]) = hc;
        sum[0] += a.x; sum[1] += a.y; sum[2] += a.z; sum[3] += a.w;
        sum[4] += c.x; sum[5] += c.y; sum[6] += c.z; sum[7] += c.w;
    }
    #pragma unroll
    for (int t = 0; t < 4; ++t) {
        red[wv][lane * 4 + t] = sum[t];
        red[wv][256 + lane * 4 + t] = sum[4 + t];
    }
    __syncthreads();
    #pragma unroll
    for (int j = 0; j < 2; ++j) {
        int col = tid + j * 256;
        float s = red[0][col] + red[1][col] + red[2][col] + red[3][col];
        atomicAdd(&accv[(size_t)b * 512 + col], s * (1.f / 1024.f));
    }
}

// ---------------- Kernel 1: W [k][n] fp32 -> Wt [n][k] bf16 --------------
__global__ __launch_bounds__(256) void wconv_kernel(
    const float* __restrict__ Wq, const float* __restrict__ Wk,
    const float* __restrict__ Wv, unsigned short* __restrict__ Wt)
{
    const float* W = (blockIdx.z == 0) ? Wq : (blockIdx.z == 1) ? Wk : Wv;
    unsigned short* o = Wt + (size_t)blockIdx.z * 512 * 512;
    __shared__ unsigned short t[64][65];
    int k0 = blockIdx.x * 64, n0 = blockIdx.y * 64;
    #pragma unroll
    for (int i = 0; i < 16; ++i) {
        int idx = i * 256 + threadIdx.x;
        int r = idx >> 6, c = idx & 63;
        t[r][c] = f2bf(W[(size_t)(k0 + r) * 512 + n0 + c]);
    }
    __syncthreads();
    #pragma unroll
    for (int i = 0; i < 16; ++i) {
        int idx = i * 256 + threadIdx.x;
        int r = idx >> 6, c = idx & 63;   // r = n, c = k
        o[(size_t)(n0 + r) * 512 + k0 + c] = t[c][r];
    }
}

__global__ __launch_bounds__(512) void biascat_kernel(
    const float* __restrict__ bq, const float* __restrict__ bk,
    const float* __restrict__ bv, float* __restrict__ bc)
{
    int n = threadIdx.x;
    bc[n] = bq[n]; bc[512 + n] = bk[n]; bc[1024 + n] = bv[n];
}

// ---------------- Kernel 2: QKV projection GEMM (m97 structure) ----------
// C = relu(X @ [Wq|Wk|Wv] + b) -> bf16 slots. 128x128 tile, 4 waves 64x64.
__global__ __launch_bounds__(256) void qkv_gemm(
    const unsigned short* __restrict__ Xb1, const unsigned short* __restrict__ Xb2,
    const unsigned short* __restrict__ Wt, const float* __restrict__ bias_cat,
    unsigned short* __restrict__ qkv)
{
    int nt = blockIdx.x;          // 0..11  (fastest: co-resident blocks share A)
    int mg = blockIdx.y;          // 0..511
    int z = mg >> 8;              // which sequence
    int m0 = (mg & 255) * 128;    // row within sequence
    int n0 = nt * 128;

    const unsigned short* X = z ? Xb2 : Xb1;

    // 16 KB staging (As|Bs) reused as 34 KB epilogue tile after final barrier
    __shared__ alignas(16) unsigned char smem[128 * 136 * 2];
    unsigned short* As = (unsigned short*)smem;            // 8 KB
    unsigned short* Bs = (unsigned short*)(smem + 8192);   // 8 KB
    unsigned short* Ct = (unsigned short*)smem;            // epilogue

    int tid = threadIdx.x;
    int lane = tid & 63, wv = tid >> 6;
    int wm = wv >> 1, wn = wv & 1;
    int q = lane >> 4, ln = lane & 15;

    f32x4_t acc[4][4] = {};

    for (int k0 = 0; k0 < 512; k0 += 32) {
        #pragma unroll
        for (int j = 0; j < 2; ++j) {
            int cbase = j * 256 + wv * 64;
            int c = cbase + lane;
            int row = c >> 2, k8 = (c & 3) * 8;
            gl2lds16(&X[(size_t)(m0 + row) * 512 + k0 + k8], &As[cbase * 8]);
            gl2lds16(&Wt[(size_t)(n0 + row) * 512 + k0 + k8], &Bs[cbase * 8]);
        }
        __syncthreads();

        bf16x8_t af[4], bfr[4];
        #pragma unroll
        for (int i = 0; i < 4; ++i)
            af[i] = *reinterpret_cast<const bf16x8_t*>(
                &As[(wm * 64 + i * 16 + ln) * 32 + q * 8]);
        #pragma unroll
        for (int j = 0; j < 4; ++j)
            bfr[j] = *reinterpret_cast<const bf16x8_t*>(
                &Bs[(wn * 64 + j * 16 + ln) * 32 + q * 8]);
        #pragma unroll
        for (int i = 0; i < 4; ++i)
            #pragma unroll
            for (int j = 0; j < 4; ++j)
                acc[i][j] = __builtin_amdgcn_mfma_f32_16x16x32_bf16(
                    af[i], bfr[j], acc[i][j], 0, 0, 0);
        __syncthreads();
    }

    // ---- epilogue: bias+relu -> bf16 tile in LDS, then coalesced stores ----
    constexpr int LDW = 136;  // 128 + 8 shorts pad
    #pragma unroll
    for (int j = 0; j < 4; ++j) {
        int nl = wn * 64 + j * 16 + ln;
        float bb = bias_cat[n0 + nl];
        #pragma unroll
        for (int i = 0; i < 4; ++i) {
            int mlb = wm * 64 + i * 16 + q * 4;
            #pragma unroll
            for (int r = 0; r < 4; ++r)
                Ct[(mlb + r) * LDW + nl] = f2bf(fmaxf(acc[i][j][r] + bb, 0.f));
        }
    }
    __syncthreads();

    int w = nt >> 2;                 // whole 128-wide tile is in one slot
    int col0 = (nt & 3) * 128;
    unsigned short* outb = qkv + (size_t)(z * 3 + w) * 32768 * 512
                               + (size_t)m0 * 512 + col0;
    #pragma unroll
    for (int it = 0; it < 8; ++it) {
        int id = it * 256 + tid;
        int row = id >> 4, ch = id & 15;
        *reinterpret_cast<uint4*>(&outb[(size_t)row * 512 + ch * 8]) =
            *reinterpret_cast<const uint4*>(&Ct[row * LDW + ch * 8]);
    }
}

// ---------------- Kernel 3: score GEMM + tanh + row-sum (m97) ------------
// a[which][b][s] += sum_t tanh( A[s,:] . B[t,:] ),  A=k_self, B=q_other
__global__ __launch_bounds__(256) void score_kernel(
    const unsigned short* __restrict__ qkv, float* __restrict__ a_out)
{
    int tt = blockIdx.x, st = blockIdx.y, z = blockIdx.z;
    int which = z >> 5, b = z & 31;
    const unsigned short* Am =
        qkv + ((size_t)(which ? 4 : 1) * 32768 + (size_t)b * 1024) * 512;
    const unsigned short* Bm =
        qkv + ((size_t)(which ? 0 : 3) * 32768 + (size_t)b * 1024) * 512;

    __shared__ alignas(16) unsigned short As[128 * 32];
    __shared__ alignas(16) unsigned short Bs[128 * 32];

    int tid = threadIdx.x;
    int lane = tid & 63, wv = tid >> 6;
    int wm = wv >> 1, wn = wv & 1;
    int q = lane >> 4, ln = lane & 15;
    int s0 = st * 128, t0 = tt * 128;

    f32x4_t acc[4][4] = {};

    for (int k0 = 0; k0 < 512; k0 += 32) {
        #pragma unroll
        for (int j = 0; j < 2; ++j) {
            int cbase = j * 256 + wv * 64;
            int c = cbase + lane;
            int row = c >> 2, kk8 = (c & 3) * 8;
            gl2lds16(&Am[(size_t)(s0 + row) * 512 + k0 + kk8], &As[cbase * 8]);
            gl2lds16(&Bm[(size_t)(t0 + row) * 512 + k0 + kk8], &Bs[cbase * 8]);
        }
        __syncthreads();

        bf16x8_t af[4], bfr[4];
        #pragma unroll
        for (int i = 0; i < 4; ++i)
            af[i] = *reinterpret_cast<const bf16x8_t*>(
                &As[(wm * 64 + i * 16 + ln) * 32 + q * 8]);
        #pragma unroll
        for (int j = 0; j < 4; ++j)
            bfr[j] = *reinterpret_cast<const bf16x8_t*>(
                &Bs[(wn * 64 + j * 16 + ln) * 32 + q * 8]);
        #pragma unroll
        for (int i = 0; i < 4; ++i)
            #pragma unroll
            for (int j = 0; j < 4; ++j)
                acc[i][j] = __builtin_amdgcn_mfma_f32_16x16x32_bf16(
                    af[i], bfr[j], acc[i][j], 0, 0, 0);
        __syncthreads();
    }

    #pragma unroll
    for (int i = 0; i < 4; ++i) {
        #pragma unroll
        for (int r = 0; r < 4; ++r) {
            float s = 0.f;
            #pragma unroll
            for (int j = 0; j < 4; ++j) s += fast_tanh(acc[i][j][r]);
            #pragma unroll
            for (int off = 1; off <= 8; off <<= 1) s += __shfl_xor(s, off, 64);
            if (ln == 0)
                atomicAdd(&a_out[(size_t)z * 1024 + s0 + wm * 64 + i * 16 + q * 4 + r], s);
        }
    }
}

// ---------------- Kernel 4: masked softmax over S=1024 -------------------
__global__ __launch_bounds__(256) void softmax_kernel(
    const float* __restrict__ a_in, const int* __restrict__ mask1,
    const int* __restrict__ mask2, float* __restrict__ w_out)
{
    int z = blockIdx.x, which = z >> 5, b = z & 31;
    const int* mask = (which ? mask2 : mask1) + (size_t)b * 1024;
    const float* a = a_in + (size_t)z * 1024;
    float* w = w_out + (size_t)z * 1024;
    int tid = threadIdx.x, lane = tid & 63, wv = tid >> 6;

    float vals[4];
    #pragma unroll
    for (int j = 0; j < 4; ++j) {
        int s = tid + j * 256;
        vals[j] = mask[s] ? -__builtin_inff() : a[s];
    }
    float m = fmaxf(fmaxf(vals[0], vals[1]), fmaxf(vals[2], vals[3]));
    #pragma unroll
    for (int off = 32; off; off >>= 1) m = fmaxf(m, __shfl_xor(m, off, 64));
    __shared__ float redm[4], redsum[4];
    if (lane == 0) redm[wv] = m;
    __syncthreads();
    m = fmaxf(fmaxf(redm[0], redm[1]), fmaxf(redm[2], redm[3]));

    float e[4], sum = 0.f;
    #pragma unroll
    for (int j = 0; j < 4; ++j) { e[j] = __expf(vals[j] - m); sum += e[j]; }
    #pragma unroll
    for (int off = 32; off; off >>= 1) sum += __shfl_xor(sum, off, 64);
    if (lane == 0) redsum[wv] = sum;
    __syncthreads();
    sum = redsum[0] + redsum[1] + redsum[2] + redsum[3];
    float inv = 1.f / sum;
    #pragma unroll
    for (int j = 0; j < 4; ++j) w[tid + j * 256] = e[j] * inv;
}

// --------- Kernel 5: acc[z][d] += sum_s w[s]*v[s,d]  (vectorized) --------
__global__ __launch_bounds__(128) void wsum_kernel(
    const unsigned short* __restrict__ qkv, const float* __restrict__ w_in,
    float* __restrict__ acc)
{
    int chunk = blockIdx.x;           // 0..7, 128 rows each
    int z = blockIdx.y, which = z >> 5, b = z & 31;
    const unsigned short* V =
        qkv + ((size_t)(which ? 5 : 2) * 32768 + (size_t)b * 1024) * 512;
    const float* w = w_in + (size_t)z * 1024;
    int d0 = threadIdx.x * 4;
    float a0 = 0.f, a1 = 0.f, a2 = 0.f, a3 = 0.f;
    int s0 = chunk * 128;
    #pragma unroll 4
    for (int s = s0; s < s0 + 128; ++s) {
        ushort4 v = *reinterpret_cast<const ushort4*>(&V[(size_t)s * 512 + d0]);
        float ws = w[s];
        a0 += ws * bf2f(v.x); a1 += ws * bf2f(v.y);
        a2 += ws * bf2f(v.z); a3 += ws * bf2f(v.w);
    }
    atomicAdd(&acc[(size_t)z * 512 + d0 + 0], a0);
    atomicAdd(&acc[(size_t)z * 512 + d0 + 1], a1);
    atomicAdd(&acc[(size_t)z * 512 + d0 + 2], a2);
    atomicAdd(&acc[(size_t)z * 512 + d0 + 3], a3);
}

// ---------------- Kernel 6: LayerNorm over D=512 -------------------------
__global__ __launch_bounds__(512) void ln_kernel(
    const float* __restrict__ acc, const float* __restrict__ gamma,
    const float* __restrict__ beta, float* __restrict__ out)
{
    int z = blockIdx.x, d = threadIdx.x;
    int lane = d & 63, wv = d >> 6;
    float x = acc[(size_t)z * 512 + d];
    float s = x;
    #pragma unroll
    for (int off = 32; off; off >>= 1) s += __shfl_xor(s, off, 64);
    __shared__ float red[8], red2[8];
    if (lane == 0) red[wv] = s;
    __syncthreads();
    float mu = 0.f;
    #pragma unroll
    for (int i = 0; i < 8; ++i) mu += red[i];
    mu *= (1.f / 512.f);
    float c = x - mu;
    float s2 = c * c;
    #pragma unroll
    for (int off = 32; off; off >>= 1) s2 += __shfl_xor(s2, off, 64);
    if (lane == 0) red2[wv] = s2;
    __syncthreads();
    float var = 0.f;
    #pragma unroll
    for (int i = 0; i < 8; ++i) var += red2[i];
    var *= (1.f / 512.f);
    out[(size_t)z * 512 + d] = c * __frsqrt_rn(var + 1e-5f) * gamma[d] + beta[d];
}

extern "C" void kernel_launch(void* const* d_in, const int* in_sizes, int n_in,
                              void* d_out, int out_size, void* d_ws, size_t ws_size,
                              hipStream_t stream) {
    const float* seq1 = (const float*)d_in[0];
    const float* seq2 = (const float*)d_in[1];
    const int* mask1 = (const int*)d_in[2];
    const int* mask2 = (const int*)d_in[3];
    const float* Wq = (const float*)d_in[4];
    const float* bq = (const float*)d_in[5];
    const float* Wk = (const float*)d_in[6];
    const float* bk = (const float*)d_in[7];
    const float* Wv = (const float*)d_in[8];
    const float* bv = (const float*)d_in[9];
    const float* gamma = (const float*)d_in[10];
    const float* beta = (const float*)d_in[11];
    float* out = (float*)d_out;

    char* ws = (char*)d_ws;
    float* a_sc = (float*)(ws);                              // 256 KB
    float* wsm = (float*)(ws + (256u << 10));                // 256 KB
    float* accv = (float*)(ws + (512u << 10));               // 128 KB
    float* bias_cat = (float*)(ws + (768u << 10));           // 6 KB
    unsigned short* Wt = (unsigned short*)(ws + (1u << 20)); // 1.5 MB
    unsigned short* Xb2 = (unsigned short*)(ws + (4ull << 20));   // 32 MB
    unsigned short* qkv = (unsigned short*)(ws + (40ull << 20));  // 192 MB
    unsigned short* Xb1 = (unsigned short*)d_in[1];  // reuse dead seq2 fp32 buf

    hipMemsetAsync(ws, 0, 640u << 10, stream);  // zero a_sc + wsm + accv

    wconv_kernel<<<dim3(8, 8, 3), 256, 0, stream>>>(Wq, Wk, Wv, Wt);
    biascat_kernel<<<1, 512, 0, stream>>>(bq, bk, bv, bias_cat);
    // seq2 first (reads d_in[1]); then seq1 overwrites d_in[1] with bf16 X1
    x2bf_kernel<<<dim3(8, 32), 256, 0, stream>>>(seq2, Xb2, accv + 32 * 512);
    x2bf_kernel<<<dim3(8, 32), 256, 0, stream>>>(seq1, Xb1, accv);
    qkv_gemm<<<dim3(12, 512), 256, 0, stream>>>(Xb1, Xb2, Wt, bias_cat, qkv);
    score_kernel<<<dim3(8, 8, 64), 256, 0, stream>>>(qkv, a_sc);
    softmax_kernel<<<64, 256, 0, stream>>>(a_sc, mask1, mask2, wsm);
    wsum_kernel<<<dim3(8, 64), 128, 0, stream>>>(qkv, wsm, accv);
    ln_kernel<<<64, 512, 0, stream>>>(accv, gamma, beta, out);
}